// Round 1
// baseline (1550.624 us; speedup 1.0000x reference)
//
#include <hip/hip_runtime.h>

#define N_NODES 50000
#define N_EDGES 800000
#define IN_DIM  128
#define EDGE_DIM 64
#define OUT_DIM 128

// ---------------------------------------------------------------------------
// zero d_out (holds segment-sum accumulator) and cnt
// ---------------------------------------------------------------------------
__global__ void zero_kernel(float* __restrict__ out, float* __restrict__ cnt) {
    const int stride = gridDim.x * blockDim.x;
    int i = blockIdx.x * blockDim.x + threadIdx.x;
    for (int j = i; j < N_NODES * OUT_DIM; j += stride) out[j] = 0.0f;
    for (int j = i; j < N_NODES; j += stride) cnt[j] = 0.0f;
}

// ---------------------------------------------------------------------------
// W2f[c][o] = sum_i W_edge[c][i] * W_ne[IN_DIM + i][o]   (c<64, o<128)
// ---------------------------------------------------------------------------
__global__ void fuse_w2_kernel(const float* __restrict__ W_edge,
                               const float* __restrict__ W_ne,
                               float* __restrict__ W2f) {
    const int idx = blockIdx.x * blockDim.x + threadIdx.x;
    if (idx >= EDGE_DIM * OUT_DIM) return;
    const int c = idx >> 7;       // /128
    const int o = idx & 127;
    float acc = 0.0f;
    for (int i = 0; i < OUT_DIM; ++i)
        acc += W_edge[c * OUT_DIM + i] * W_ne[(IN_DIM + i) * OUT_DIM + o];
    W2f[c * OUT_DIM + o] = acc;
}

// ---------------------------------------------------------------------------
// Edge kernel: m_e = relu(nfeat[src] @ W1 + efeat @ W2f + b_ne)
//              atomicAdd into out[dst], cnt[dst]
// 256 threads: half = tid>>7 picks one of 2 edges per pass, o = tid&127 is
// the output column. Each thread holds its column of W1 (128) and W2f (64)
// in registers (statically unrolled -> stays in VGPRs).
// ---------------------------------------------------------------------------
__global__ __launch_bounds__(256, 2) void edge_kernel(
    const float* __restrict__ nfeat, const float* __restrict__ efeat,
    const int* __restrict__ src, const int* __restrict__ dst,
    const float* __restrict__ W_ne, const float* __restrict__ b_ne,
    const float* __restrict__ W2f,
    float* __restrict__ out, float* __restrict__ cnt) {

    __shared__ float h_lds[2][IN_DIM];
    __shared__ float e_lds[2][EDGE_DIM];

    const int tid  = threadIdx.x;
    const int half = tid >> 7;
    const int o    = tid & 127;

    float w1[IN_DIM];
#pragma unroll
    for (int k = 0; k < IN_DIM; ++k) w1[k] = W_ne[k * OUT_DIM + o];
    float w2[EDGE_DIM];
#pragma unroll
    for (int c = 0; c < EDGE_DIM; ++c) w2[c] = W2f[c * OUT_DIM + o];
    const float bias = b_ne[o];

    const int npairs = N_EDGES / 2;
    for (int p = blockIdx.x; p < npairs; p += gridDim.x) {
        const int e = 2 * p + half;
        const int s = src[e];
        h_lds[half][o] = nfeat[s * IN_DIM + o];
        if (o < EDGE_DIM) e_lds[half][o] = efeat[e * EDGE_DIM + o];
        __syncthreads();

        float acc = bias;
#pragma unroll
        for (int k = 0; k < IN_DIM; ++k)
            acc = fmaf(h_lds[half][k], w1[k], acc);
#pragma unroll
        for (int c = 0; c < EDGE_DIM; ++c)
            acc = fmaf(e_lds[half][c], w2[c], acc);
        acc = fmaxf(acc, 0.0f);

        const int d = dst[e];
        atomicAdd(out + d * OUT_DIM + o, acc);
        if (o == 0) atomicAdd(cnt + d, 1.0f);
        __syncthreads();
    }
}

// ---------------------------------------------------------------------------
// Node kernel: out[n] = out[n] / max(cnt[n],1) + nfeat[n] @ W_self + b_self
// ---------------------------------------------------------------------------
__global__ __launch_bounds__(256, 2) void node_kernel(
    const float* __restrict__ nfeat, const float* __restrict__ W_self,
    const float* __restrict__ b_self, const float* __restrict__ cnt,
    float* __restrict__ out) {

    __shared__ float h_lds[2][IN_DIM];
    const int tid  = threadIdx.x;
    const int half = tid >> 7;
    const int o    = tid & 127;

    float w[IN_DIM];
#pragma unroll
    for (int k = 0; k < IN_DIM; ++k) w[k] = W_self[k * OUT_DIM + o];
    const float bias = b_self[o];

    const int npairs = (N_NODES + 1) / 2;
    for (int p = blockIdx.x; p < npairs; p += gridDim.x) {
        const int n = 2 * p + half;
        if (n < N_NODES) h_lds[half][o] = nfeat[n * IN_DIM + o];
        __syncthreads();
        if (n < N_NODES) {
            float acc = bias;
#pragma unroll
            for (int k = 0; k < IN_DIM; ++k)
                acc = fmaf(h_lds[half][k], w[k], acc);
            const float inv = 1.0f / fmaxf(cnt[n], 1.0f);
            out[n * OUT_DIM + o] = out[n * OUT_DIM + o] * inv + acc;
        }
        __syncthreads();
    }
}

// ---------------------------------------------------------------------------
extern "C" void kernel_launch(void* const* d_in, const int* in_sizes, int n_in,
                              void* d_out, int out_size, void* d_ws, size_t ws_size,
                              hipStream_t stream) {
    const float* nfeat  = (const float*)d_in[0];
    const float* efeat  = (const float*)d_in[1];
    const int*   src    = (const int*)d_in[2];
    const int*   dst    = (const int*)d_in[3];
    const float* W_edge = (const float*)d_in[4];
    const float* W_ne   = (const float*)d_in[5];
    const float* b_ne   = (const float*)d_in[6];
    const float* W_self = (const float*)d_in[7];
    const float* b_self = (const float*)d_in[8];

    float* out = (float*)d_out;
    float* W2f = (float*)d_ws;                       // 64*128 floats
    float* cnt = W2f + EDGE_DIM * OUT_DIM;           // N_NODES floats

    zero_kernel<<<2048, 256, 0, stream>>>(out, cnt);
    fuse_w2_kernel<<<(EDGE_DIM * OUT_DIM + 255) / 256, 256, 0, stream>>>(W_edge, W_ne, W2f);
    edge_kernel<<<2048, 256, 0, stream>>>(nfeat, efeat, src, dst, W_ne, b_ne, W2f, out, cnt);
    node_kernel<<<1024, 256, 0, stream>>>(nfeat, W_self, b_self, cnt, out);
}

// Round 2
// 569.027 us; speedup vs baseline: 2.7250x; 2.7250x over previous
//
#include <hip/hip_runtime.h>

#define N_NODES 50000
#define N_EDGES 800000
#define IN_DIM  128
#define EDGE_DIM 64
#define OUT_DIM 128

typedef __attribute__((ext_vector_type(8))) short bf16x8;
typedef __attribute__((ext_vector_type(4))) float f32x4;

__device__ __forceinline__ unsigned short f2bf(float f) {
    union { float f; unsigned u; } x; x.f = f;
    unsigned r = x.u + 0x7FFFu + ((x.u >> 16) & 1u);
    return (unsigned short)(r >> 16);
}
__device__ __forceinline__ float bf2f(unsigned short h) {
    union { unsigned u; float f; } x; x.u = ((unsigned)h) << 16;
    return x.f;
}
__device__ __forceinline__ bf16x8 pack8(const float* v) {
    bf16x8 r;
#pragma unroll
    for (int i = 0; i < 8; ++i) r[i] = (short)f2bf(v[i]);
    return r;
}

// ---------------------------------------------------------------------------
// zero d_out (segment-sum accumulator) and cnt
// ---------------------------------------------------------------------------
__global__ void zero_kernel(float* __restrict__ out, float* __restrict__ cnt) {
    const int stride = gridDim.x * blockDim.x;
    int i = blockIdx.x * blockDim.x + threadIdx.x;
    float4 z = {0.f, 0.f, 0.f, 0.f};
    for (int j = i; j < (N_NODES * OUT_DIM) / 4; j += stride) ((float4*)out)[j] = z;
    for (int j = i; j < N_NODES / 4; j += stride) ((float4*)cnt)[j] = z;
    if (i == 0) { cnt[49996] = 0.f; cnt[49997] = 0.f; cnt[49998] = 0.f; cnt[49999] = 0.f; }
}

// ---------------------------------------------------------------------------
// W2fT[o][c] = sum_i W_edge[c][i] * W_ne[IN_DIM + i][o]   (c<64, o<128)
// stored TRANSPOSED [128][64] fp32 so MFMA B-fragments are contiguous in k.
// ---------------------------------------------------------------------------
__global__ void fuse_w2_kernel(const float* __restrict__ W_edge,
                               const float* __restrict__ W_ne,
                               float* __restrict__ W2fT) {
    const int idx = blockIdx.x * blockDim.x + threadIdx.x;
    if (idx >= EDGE_DIM * OUT_DIM) return;
    const int c = idx >> 7;
    const int o = idx & 127;
    float acc = 0.0f;
    for (int i = 0; i < OUT_DIM; ++i)
        acc += W_edge[c * OUT_DIM + i] * W_ne[(IN_DIM + i) * OUT_DIM + o];
    W2fT[o * EDGE_DIM + c] = acc;
}

// ---------------------------------------------------------------------------
// Node GEMM (VALU fp32): Y(bf16)[r][o] = X[r] @ W (+ bias). 128 threads = one
// column each, 4 rows per pass (4 independent FMA chains), LDS float4 broadcast.
// ---------------------------------------------------------------------------
__global__ __launch_bounds__(128, 3) void node_gemm_kernel(
    const float* __restrict__ X, const float* __restrict__ W,
    const float* __restrict__ bias, unsigned short* __restrict__ Y, int nrows) {
    __shared__ float4 h[4][32];
    const int o = threadIdx.x;
    float w[128];
#pragma unroll
    for (int k = 0; k < 128; ++k) w[k] = W[k * OUT_DIM + o];
    const float b = bias ? bias[o] : 0.0f;
    const int npass = nrows >> 2;
    for (int p = blockIdx.x; p < npass; p += gridDim.x) {
        const int r0 = p * 4;
        h[o >> 5][o & 31] = ((const float4*)(X + (size_t)r0 * 128))[o];
        __syncthreads();
        float a0 = b, a1 = b, a2 = b, a3 = b;
#pragma unroll
        for (int k4 = 0; k4 < 32; ++k4) {
            float4 h0 = h[0][k4], h1 = h[1][k4], h2 = h[2][k4], h3 = h[3][k4];
            a0 = fmaf(h0.x, w[4*k4+0], a0); a0 = fmaf(h0.y, w[4*k4+1], a0);
            a0 = fmaf(h0.z, w[4*k4+2], a0); a0 = fmaf(h0.w, w[4*k4+3], a0);
            a1 = fmaf(h1.x, w[4*k4+0], a1); a1 = fmaf(h1.y, w[4*k4+1], a1);
            a1 = fmaf(h1.z, w[4*k4+2], a1); a1 = fmaf(h1.w, w[4*k4+3], a1);
            a2 = fmaf(h2.x, w[4*k4+0], a2); a2 = fmaf(h2.y, w[4*k4+1], a2);
            a2 = fmaf(h2.z, w[4*k4+2], a2); a2 = fmaf(h2.w, w[4*k4+3], a2);
            a3 = fmaf(h3.x, w[4*k4+0], a3); a3 = fmaf(h3.y, w[4*k4+1], a3);
            a3 = fmaf(h3.z, w[4*k4+2], a3); a3 = fmaf(h3.w, w[4*k4+3], a3);
        }
        Y[(size_t)(r0 + 0) * 128 + o] = f2bf(a0);
        Y[(size_t)(r0 + 1) * 128 + o] = f2bf(a1);
        Y[(size_t)(r0 + 2) * 128 + o] = f2bf(a2);
        Y[(size_t)(r0 + 3) * 128 + o] = f2bf(a3);
        __syncthreads();
    }
}

// ---------------------------------------------------------------------------
// Fused edge kernel: per 128-edge tile
//   E2 = efeat_tile(bf16, swizzled LDS) @ W2fT(register B-frags) via MFMA
//   m  = relu(E2 + H1[src] + b_ne);  atomicAdd(out[dst], m); cnt[dst]+=1
// 256 threads = 4 waves; wave w owns rows w*32..w*32+31 (2 m-tiles),
// all 8 n-tiles, K=64 (2 mfma_16x16x32 steps).
// ---------------------------------------------------------------------------
__global__ __launch_bounds__(256, 2) void edge_mfma_kernel(
    const float* __restrict__ efeat, const int* __restrict__ src,
    const int* __restrict__ dst, const float* __restrict__ W2fT,
    const float* __restrict__ b_ne, const unsigned short* __restrict__ H1,
    float* __restrict__ out, float* __restrict__ cnt) {

    __shared__ __align__(16) char Ab[128 * 64 * 2];  // bf16 A-tile, XOR-swizzled

    const int tid  = threadIdx.x;
    const int w    = tid >> 6;
    const int l    = tid & 63;
    const int lrow = l & 15;
    const int lq   = l >> 4;

    // B fragments (W2fT) + bias, loaded once per block
    bf16x8 Bf[8][2];
    float bias[8];
#pragma unroll
    for (int nt = 0; nt < 8; ++nt) {
        bias[nt] = b_ne[nt * 16 + lrow];
#pragma unroll
        for (int kk = 0; kk < 2; ++kk) {
            const float* wp = W2fT + (nt * 16 + lrow) * 64 + kk * 32 + lq * 8;
            float tmp[8];
#pragma unroll
            for (int j = 0; j < 8; ++j) tmp[j] = wp[j];
            Bf[nt][kk] = pack8(tmp);
        }
    }

    const int ntiles = N_EDGES / 128;
    const int srow = tid >> 1;              // staging: row within tile
    const int skh  = (tid & 1) * 32;        // staging: k-half (elements)

    for (int tile = blockIdx.x; tile < ntiles; tile += gridDim.x) {
        const int e0 = tile * 128;

        // ---- stage A tile: 32 fp32 -> 32 bf16 per thread, swizzled writes
        const float4* ep = (const float4*)(efeat + (size_t)(e0 + srow) * 64 + skh);
#pragma unroll
        for (int j = 0; j < 4; ++j) {
            float4 x = ep[2 * j], y = ep[2 * j + 1];
            float tmp[8] = {x.x, x.y, x.z, x.w, y.x, y.y, y.z, y.w};
            bf16x8 f = pack8(tmp);
            int addr = (srow * 128 + skh * 2 + j * 16) ^ ((srow & 7) << 4);
            *(bf16x8*)(Ab + addr) = f;
        }
        __syncthreads();

        // ---- MFMA
        f32x4 acc[2][8];
#pragma unroll
        for (int mt = 0; mt < 2; ++mt)
#pragma unroll
            for (int nt = 0; nt < 8; ++nt) {
                acc[mt][nt][0] = bias[nt]; acc[mt][nt][1] = bias[nt];
                acc[mt][nt][2] = bias[nt]; acc[mt][nt][3] = bias[nt];
            }
        bf16x8 Af[2][2];
#pragma unroll
        for (int mt = 0; mt < 2; ++mt)
#pragma unroll
            for (int kk = 0; kk < 2; ++kk) {
                int row  = w * 32 + mt * 16 + lrow;
                int addr = (row * 128 + kk * 64 + lq * 16) ^ ((row & 7) << 4);
                Af[mt][kk] = *(const bf16x8*)(Ab + addr);
            }
#pragma unroll
        for (int mt = 0; mt < 2; ++mt)
#pragma unroll
            for (int nt = 0; nt < 8; ++nt) {
                acc[mt][nt] = __builtin_amdgcn_mfma_f32_16x16x32_bf16(Af[mt][0], Bf[nt][0], acc[mt][nt], 0, 0, 0);
                acc[mt][nt] = __builtin_amdgcn_mfma_f32_16x16x32_bf16(Af[mt][1], Bf[nt][1], acc[mt][nt], 0, 0, 0);
            }

        // ---- epilogue: gather H1[src], relu, atomic scatter by dst
#pragma unroll
        for (int mt = 0; mt < 2; ++mt) {
#pragma unroll
            for (int j = 0; j < 4; ++j) {
                const int row = w * 32 + mt * 16 + lq * 4 + j;
                const int e   = e0 + row;
                const int s   = src[e];
                const int d   = dst[e];
                if (lrow == 0) atomicAdd(cnt + d, 1.0f);
                const unsigned short* hp = H1 + (size_t)s * 128;
                float* op = out + (size_t)d * 128;
#pragma unroll
                for (int nt = 0; nt < 8; ++nt) {
                    const int col = nt * 16 + lrow;
                    float v = fmaxf(acc[mt][nt][j] + bf2f(hp[col]), 0.0f);
                    atomicAdd(op + col, v);
                }
            }
        }
        __syncthreads();
    }
}

// ---------------------------------------------------------------------------
// finalize: out[n] = out[n]/max(cnt[n],1) + HS[n]
// ---------------------------------------------------------------------------
__global__ void finalize_kernel(float* __restrict__ out, const float* __restrict__ cnt,
                                const unsigned short* __restrict__ HS) {
    const int stride = gridDim.x * blockDim.x;
    for (int i = blockIdx.x * blockDim.x + threadIdx.x; i < N_NODES * 32; i += stride) {
        const int row = i >> 5;
        const float inv = 1.0f / fmaxf(cnt[row], 1.0f);
        float4 v = ((const float4*)out)[i];
        ushort4 hs = ((const ushort4*)HS)[i];
        float4 r;
        r.x = v.x * inv + bf2f(hs.x);
        r.y = v.y * inv + bf2f(hs.y);
        r.z = v.z * inv + bf2f(hs.z);
        r.w = v.w * inv + bf2f(hs.w);
        ((float4*)out)[i] = r;
    }
}

// ---------------------------------------------------------------------------
// Fallback path (round-1 kernels) if ws_size is too small for bf16 pipeline.
// ---------------------------------------------------------------------------
__global__ __launch_bounds__(256, 2) void fb_edge_kernel(
    const float* __restrict__ nfeat, const float* __restrict__ efeat,
    const int* __restrict__ src, const int* __restrict__ dst,
    const float* __restrict__ W_ne, const float* __restrict__ b_ne,
    const float* __restrict__ W2fT,
    float* __restrict__ out, float* __restrict__ cnt) {
    __shared__ float h_lds[2][IN_DIM];
    __shared__ float e_lds[2][EDGE_DIM];
    const int tid = threadIdx.x, half = tid >> 7, o = tid & 127;
    float w1[IN_DIM];
#pragma unroll
    for (int k = 0; k < IN_DIM; ++k) w1[k] = W_ne[k * OUT_DIM + o];
    float w2[EDGE_DIM];
#pragma unroll
    for (int c = 0; c < EDGE_DIM; ++c) w2[c] = W2fT[o * EDGE_DIM + c];
    const float bias = b_ne[o];
    const int npairs = N_EDGES / 2;
    for (int p = blockIdx.x; p < npairs; p += gridDim.x) {
        const int e = 2 * p + half;
        const int s = src[e];
        h_lds[half][o] = nfeat[s * IN_DIM + o];
        if (o < EDGE_DIM) e_lds[half][o] = efeat[(size_t)e * EDGE_DIM + o];
        __syncthreads();
        float acc = bias;
#pragma unroll
        for (int k = 0; k < IN_DIM; ++k) acc = fmaf(h_lds[half][k], w1[k], acc);
#pragma unroll
        for (int c = 0; c < EDGE_DIM; ++c) acc = fmaf(e_lds[half][c], w2[c], acc);
        acc = fmaxf(acc, 0.0f);
        const int d = dst[e];
        atomicAdd(out + (size_t)d * OUT_DIM + o, acc);
        if (o == 0) atomicAdd(cnt + d, 1.0f);
        __syncthreads();
    }
}

__global__ __launch_bounds__(256, 2) void fb_node_kernel(
    const float* __restrict__ nfeat, const float* __restrict__ W_self,
    const float* __restrict__ b_self, const float* __restrict__ cnt,
    float* __restrict__ out) {
    __shared__ float h_lds[2][IN_DIM];
    const int tid = threadIdx.x, half = tid >> 7, o = tid & 127;
    float w[IN_DIM];
#pragma unroll
    for (int k = 0; k < IN_DIM; ++k) w[k] = W_self[k * OUT_DIM + o];
    const float bias = b_self[o];
    const int npairs = (N_NODES + 1) / 2;
    for (int p = blockIdx.x; p < npairs; p += gridDim.x) {
        const int n = 2 * p + half;
        if (n < N_NODES) h_lds[half][o] = nfeat[n * IN_DIM + o];
        __syncthreads();
        if (n < N_NODES) {
            float acc = bias;
#pragma unroll
            for (int k = 0; k < IN_DIM; ++k) acc = fmaf(h_lds[half][k], w[k], acc);
            const float inv = 1.0f / fmaxf(cnt[n], 1.0f);
            out[(size_t)n * OUT_DIM + o] = out[(size_t)n * OUT_DIM + o] * inv + acc;
        }
        __syncthreads();
    }
}

// ---------------------------------------------------------------------------
extern "C" void kernel_launch(void* const* d_in, const int* in_sizes, int n_in,
                              void* d_out, int out_size, void* d_ws, size_t ws_size,
                              hipStream_t stream) {
    const float* nfeat  = (const float*)d_in[0];
    const float* efeat  = (const float*)d_in[1];
    const int*   src    = (const int*)d_in[2];
    const int*   dst    = (const int*)d_in[3];
    const float* W_edge = (const float*)d_in[4];
    const float* W_ne   = (const float*)d_in[5];
    const float* b_ne   = (const float*)d_in[6];
    const float* W_self = (const float*)d_in[7];
    const float* b_self = (const float*)d_in[8];

    float* out = (float*)d_out;

    // ws layout
    char* ws = (char*)d_ws;
    float* W2fT = (float*)ws;                                     // 32768 B
    float* cnt  = (float*)(ws + 32768);                           // 200000 B
    unsigned short* H1 = (unsigned short*)(ws + 233472);          // 12.8 MB
    unsigned short* HS = (unsigned short*)(ws + 233472 + 12800000);
    const size_t NEED = 233472 + 2 * 12800000;

    if (ws_size >= NEED) {
        zero_kernel<<<1024, 256, 0, stream>>>(out, cnt);
        fuse_w2_kernel<<<32, 256, 0, stream>>>(W_edge, W_ne, W2fT);
        node_gemm_kernel<<<1536, 128, 0, stream>>>(nfeat, W_ne, nullptr, H1, N_NODES);
        node_gemm_kernel<<<1536, 128, 0, stream>>>(nfeat, W_self, b_self, HS, N_NODES);
        edge_mfma_kernel<<<2048, 256, 0, stream>>>(efeat, src, dst, W2fT, b_ne, H1, out, cnt);
        finalize_kernel<<<1024, 256, 0, stream>>>(out, cnt, HS);
    } else {
        // fallback: round-1 fp32 path (needs 232 KB ws, proven available)
        zero_kernel<<<1024, 256, 0, stream>>>(out, cnt);
        fuse_w2_kernel<<<32, 256, 0, stream>>>(W_edge, W_ne, W2fT);
        fb_edge_kernel<<<2048, 256, 0, stream>>>(nfeat, efeat, src, dst, W_ne, b_ne, W2fT, out, cnt);
        fb_node_kernel<<<1024, 256, 0, stream>>>(nfeat, W_self, b_self, cnt, out);
    }
}

// Round 3
// 484.809 us; speedup vs baseline: 3.1984x; 1.1737x over previous
//
#include <hip/hip_runtime.h>

#define N_NODES 50000
#define N_EDGES 800000
#define IN_DIM  128
#define EDGE_DIM 64
#define OUT_DIM 128

typedef __attribute__((ext_vector_type(8))) short bf16x8;
typedef __attribute__((ext_vector_type(4))) float f32x4;
typedef unsigned short u16;

__device__ __forceinline__ u16 f2bf(float f) {
    union { float f; unsigned u; } x; x.f = f;
    unsigned r = x.u + 0x7FFFu + ((x.u >> 16) & 1u);
    return (u16)(r >> 16);
}
__device__ __forceinline__ float bf2f(u16 h) {
    union { unsigned u; float f; } x; x.u = ((unsigned)h) << 16;
    return x.f;
}
__device__ __forceinline__ bf16x8 pack8(const float* v) {
    bf16x8 r;
#pragma unroll
    for (int i = 0; i < 8; ++i) r[i] = (short)f2bf(v[i]);
    return r;
}

// ---------------------------------------------------------------------------
// W2fT[o][c] = sum_i W_edge[c][i] * W_ne[IN_DIM + i][o]  (stored [128][64])
// ---------------------------------------------------------------------------
__global__ void fuse_w2_kernel(const float* __restrict__ W_edge,
                               const float* __restrict__ W_ne,
                               float* __restrict__ W2fT) {
    const int idx = blockIdx.x * blockDim.x + threadIdx.x;
    if (idx >= EDGE_DIM * OUT_DIM) return;
    const int c = idx >> 7;
    const int o = idx & 127;
    float acc = 0.0f;
    for (int i = 0; i < OUT_DIM; ++i)
        acc += W_edge[c * OUT_DIM + i] * W_ne[(IN_DIM + i) * OUT_DIM + o];
    W2fT[o * EDGE_DIM + c] = acc;
}

// ---------------------------------------------------------------------------
// Node GEMM (VALU fp32): Y(bf16) = X @ W (+bias)
// ---------------------------------------------------------------------------
__global__ __launch_bounds__(128, 3) void node_gemm_kernel(
    const float* __restrict__ X, const float* __restrict__ W,
    const float* __restrict__ bias, u16* __restrict__ Y, int nrows) {
    __shared__ float4 h[4][32];
    const int o = threadIdx.x;
    float w[128];
#pragma unroll
    for (int k = 0; k < 128; ++k) w[k] = W[k * OUT_DIM + o];
    const float b = bias ? bias[o] : 0.0f;
    const int npass = nrows >> 2;
    for (int p = blockIdx.x; p < npass; p += gridDim.x) {
        const int r0 = p * 4;
        h[o >> 5][o & 31] = ((const float4*)(X + (size_t)r0 * 128))[o];
        __syncthreads();
        float a0 = b, a1 = b, a2 = b, a3 = b;
#pragma unroll
        for (int k4 = 0; k4 < 32; ++k4) {
            float4 h0 = h[0][k4], h1 = h[1][k4], h2 = h[2][k4], h3 = h[3][k4];
            a0 = fmaf(h0.x, w[4*k4+0], a0); a0 = fmaf(h0.y, w[4*k4+1], a0);
            a0 = fmaf(h0.z, w[4*k4+2], a0); a0 = fmaf(h0.w, w[4*k4+3], a0);
            a1 = fmaf(h1.x, w[4*k4+0], a1); a1 = fmaf(h1.y, w[4*k4+1], a1);
            a1 = fmaf(h1.z, w[4*k4+2], a1); a1 = fmaf(h1.w, w[4*k4+3], a1);
            a2 = fmaf(h2.x, w[4*k4+0], a2); a2 = fmaf(h2.y, w[4*k4+1], a2);
            a2 = fmaf(h2.z, w[4*k4+2], a2); a2 = fmaf(h2.w, w[4*k4+3], a2);
            a3 = fmaf(h3.x, w[4*k4+0], a3); a3 = fmaf(h3.y, w[4*k4+1], a3);
            a3 = fmaf(h3.z, w[4*k4+2], a3); a3 = fmaf(h3.w, w[4*k4+3], a3);
        }
        Y[(size_t)(r0 + 0) * 128 + o] = f2bf(a0);
        Y[(size_t)(r0 + 1) * 128 + o] = f2bf(a1);
        Y[(size_t)(r0 + 2) * 128 + o] = f2bf(a2);
        Y[(size_t)(r0 + 3) * 128 + o] = f2bf(a3);
        __syncthreads();
    }
}

// ---------------------------------------------------------------------------
// CSR build: rank/count -> scan -> scatter permutation
// ---------------------------------------------------------------------------
__global__ void count_rank_kernel(const int* __restrict__ dst,
                                  int* __restrict__ counts, int* __restrict__ rank) {
    const int e = blockIdx.x * blockDim.x + threadIdx.x;
    if (e < N_EDGES) rank[e] = atomicAdd(&counts[dst[e]], 1);
}

#define SCAN_T 1024
#define SCAN_CHUNK 49   // 1024*49 = 50176 >= 50000
__global__ void scan_kernel(const int* __restrict__ counts, int* __restrict__ off) {
    __shared__ int part[SCAN_T];
    const int t = threadIdx.x;
    const int base = t * SCAN_CHUNK;
    int s = 0;
    for (int k = 0; k < SCAN_CHUNK; ++k) {
        const int i = base + k;
        if (i < N_NODES) s += counts[i];
    }
    part[t] = s;
    __syncthreads();
    for (int d = 1; d < SCAN_T; d <<= 1) {
        int v = (t >= d) ? part[t - d] : 0;
        __syncthreads();
        part[t] += v;
        __syncthreads();
    }
    int excl = part[t] - s;
    for (int k = 0; k < SCAN_CHUNK; ++k) {
        const int i = base + k;
        if (i < N_NODES) { off[i] = excl; excl += counts[i]; }
    }
    if (t == SCAN_T - 1) off[N_NODES] = excl;
}

__global__ void scatter_kernel(const int* __restrict__ dst, const int* __restrict__ rank,
                               const int* __restrict__ off, int* __restrict__ eid) {
    const int e = blockIdx.x * blockDim.x + threadIdx.x;
    if (e < N_EDGES) eid[off[dst[e]] + rank[e]] = e;
}

// ---------------------------------------------------------------------------
// Phase A: m[e] = relu(efeat[e] @ W2f + H1[src[e]] + b_ne), stored bf16.
// Per 128-edge tile: efeat -> bf16 swizzled LDS, MFMA 16x16x32, epilogue
// gathers H1 and writes m sequentially (NO atomics).
// ---------------------------------------------------------------------------
__global__ __launch_bounds__(256, 2) void edge_gemm_m_kernel(
    const float* __restrict__ efeat, const int* __restrict__ src,
    const float* __restrict__ W2fT, const float* __restrict__ b_ne,
    const u16* __restrict__ H1, u16* __restrict__ mbuf) {

    __shared__ __align__(16) char Ab[128 * 64 * 2];

    const int tid  = threadIdx.x;
    const int w    = tid >> 6;
    const int l    = tid & 63;
    const int lrow = l & 15;
    const int lq   = l >> 4;

    bf16x8 Bf[8][2];
    float bias[8];
#pragma unroll
    for (int nt = 0; nt < 8; ++nt) {
        bias[nt] = b_ne[nt * 16 + lrow];
#pragma unroll
        for (int kk = 0; kk < 2; ++kk) {
            const float* wp = W2fT + (nt * 16 + lrow) * 64 + kk * 32 + lq * 8;
            float tmp[8];
#pragma unroll
            for (int j = 0; j < 8; ++j) tmp[j] = wp[j];
            Bf[nt][kk] = pack8(tmp);
        }
    }

    const int ntiles = N_EDGES / 128;
    const int srow = tid >> 1;
    const int skh  = (tid & 1) * 32;

    for (int tile = blockIdx.x; tile < ntiles; tile += gridDim.x) {
        const int e0 = tile * 128;

        const float4* ep = (const float4*)(efeat + (size_t)(e0 + srow) * 64 + skh);
#pragma unroll
        for (int j = 0; j < 4; ++j) {
            float4 x = ep[2 * j], y = ep[2 * j + 1];
            float tmp[8] = {x.x, x.y, x.z, x.w, y.x, y.y, y.z, y.w};
            bf16x8 f = pack8(tmp);
            int addr = (srow * 128 + skh * 2 + j * 16) ^ ((srow & 7) << 4);
            *(bf16x8*)(Ab + addr) = f;
        }
        __syncthreads();

        f32x4 acc[2][8];
#pragma unroll
        for (int mt = 0; mt < 2; ++mt)
#pragma unroll
            for (int nt = 0; nt < 8; ++nt) {
                acc[mt][nt][0] = bias[nt]; acc[mt][nt][1] = bias[nt];
                acc[mt][nt][2] = bias[nt]; acc[mt][nt][3] = bias[nt];
            }
        bf16x8 Af[2][2];
#pragma unroll
        for (int mt = 0; mt < 2; ++mt)
#pragma unroll
            for (int kk = 0; kk < 2; ++kk) {
                int row  = w * 32 + mt * 16 + lrow;
                int addr = (row * 128 + kk * 64 + lq * 16) ^ ((row & 7) << 4);
                Af[mt][kk] = *(const bf16x8*)(Ab + addr);
            }
#pragma unroll
        for (int mt = 0; mt < 2; ++mt)
#pragma unroll
            for (int nt = 0; nt < 8; ++nt) {
                acc[mt][nt] = __builtin_amdgcn_mfma_f32_16x16x32_bf16(Af[mt][0], Bf[nt][0], acc[mt][nt], 0, 0, 0);
                acc[mt][nt] = __builtin_amdgcn_mfma_f32_16x16x32_bf16(Af[mt][1], Bf[nt][1], acc[mt][nt], 0, 0, 0);
            }

#pragma unroll
        for (int mt = 0; mt < 2; ++mt) {
#pragma unroll
            for (int j = 0; j < 4; ++j) {
                const int row = w * 32 + mt * 16 + lq * 4 + j;
                const int e   = e0 + row;
                const int s   = src[e];
                const u16* hp = H1 + (size_t)s * 128;
                u16* mp = mbuf + (size_t)e * 128;
#pragma unroll
                for (int nt = 0; nt < 8; ++nt) {
                    const int col = nt * 16 + lrow;
                    float v = fmaxf(acc[mt][nt][j] + bf2f(hp[col]), 0.0f);
                    mp[col] = f2bf(v);
                }
            }
        }
        __syncthreads();
    }
}

// ---------------------------------------------------------------------------
// CSR reduce: out[n] = (sum_{slot in [off[n],off[n+1])} m[eid[slot]]) / max(c,1)
//             + HS[n].  128 threads per node, no atomics, out written once.
// ---------------------------------------------------------------------------
__global__ __launch_bounds__(256, 4) void csr_reduce_kernel(
    const int* __restrict__ eid, const int* __restrict__ off,
    const u16* __restrict__ mbuf, const u16* __restrict__ HS,
    float* __restrict__ out) {
    const int n = blockIdx.x * 2 + (threadIdx.x >> 7);
    const int o = threadIdx.x & 127;
    if (n >= N_NODES) return;
    const int s0 = off[n], s1 = off[n + 1];
    float acc = 0.0f;
    int s = s0;
    for (; s + 4 <= s1; s += 4) {
        const int e0 = eid[s], e1 = eid[s + 1], e2 = eid[s + 2], e3 = eid[s + 3];
        float v0 = bf2f(mbuf[(size_t)e0 * 128 + o]);
        float v1 = bf2f(mbuf[(size_t)e1 * 128 + o]);
        float v2 = bf2f(mbuf[(size_t)e2 * 128 + o]);
        float v3 = bf2f(mbuf[(size_t)e3 * 128 + o]);
        acc += (v0 + v1) + (v2 + v3);
    }
    for (; s < s1; ++s) acc += bf2f(mbuf[(size_t)eid[s] * 128 + o]);
    const int c = s1 - s0;
    const float inv = (c > 0) ? 1.0f / (float)c : 0.0f;
    out[(size_t)n * 128 + o] = acc * inv + bf2f(HS[(size_t)n * 128 + o]);
}

// ---------------------------------------------------------------------------
// ----- round-2 fallback kernels (used only if ws too small for CSR path) ---
// ---------------------------------------------------------------------------
__global__ void zero_kernel(float* __restrict__ out, float* __restrict__ cnt) {
    const int stride = gridDim.x * blockDim.x;
    int i = blockIdx.x * blockDim.x + threadIdx.x;
    float4 z = {0.f, 0.f, 0.f, 0.f};
    for (int j = i; j < (N_NODES * OUT_DIM) / 4; j += stride) ((float4*)out)[j] = z;
    for (int j = i; j < N_NODES / 4; j += stride) ((float4*)cnt)[j] = z;
    if (i == 0) { cnt[49996] = 0.f; cnt[49997] = 0.f; cnt[49998] = 0.f; cnt[49999] = 0.f; }
}

__global__ __launch_bounds__(256, 2) void edge_mfma_kernel(
    const float* __restrict__ efeat, const int* __restrict__ src,
    const int* __restrict__ dst, const float* __restrict__ W2fT,
    const float* __restrict__ b_ne, const u16* __restrict__ H1,
    float* __restrict__ out, float* __restrict__ cnt) {

    __shared__ __align__(16) char Ab[128 * 64 * 2];
    const int tid  = threadIdx.x;
    const int w    = tid >> 6;
    const int l    = tid & 63;
    const int lrow = l & 15;
    const int lq   = l >> 4;

    bf16x8 Bf[8][2];
    float bias[8];
#pragma unroll
    for (int nt = 0; nt < 8; ++nt) {
        bias[nt] = b_ne[nt * 16 + lrow];
#pragma unroll
        for (int kk = 0; kk < 2; ++kk) {
            const float* wp = W2fT + (nt * 16 + lrow) * 64 + kk * 32 + lq * 8;
            float tmp[8];
#pragma unroll
            for (int j = 0; j < 8; ++j) tmp[j] = wp[j];
            Bf[nt][kk] = pack8(tmp);
        }
    }
    const int ntiles = N_EDGES / 128;
    const int srow = tid >> 1;
    const int skh  = (tid & 1) * 32;

    for (int tile = blockIdx.x; tile < ntiles; tile += gridDim.x) {
        const int e0 = tile * 128;
        const float4* ep = (const float4*)(efeat + (size_t)(e0 + srow) * 64 + skh);
#pragma unroll
        for (int j = 0; j < 4; ++j) {
            float4 x = ep[2 * j], y = ep[2 * j + 1];
            float tmp[8] = {x.x, x.y, x.z, x.w, y.x, y.y, y.z, y.w};
            bf16x8 f = pack8(tmp);
            int addr = (srow * 128 + skh * 2 + j * 16) ^ ((srow & 7) << 4);
            *(bf16x8*)(Ab + addr) = f;
        }
        __syncthreads();

        f32x4 acc[2][8];
#pragma unroll
        for (int mt = 0; mt < 2; ++mt)
#pragma unroll
            for (int nt = 0; nt < 8; ++nt) {
                acc[mt][nt][0] = bias[nt]; acc[mt][nt][1] = bias[nt];
                acc[mt][nt][2] = bias[nt]; acc[mt][nt][3] = bias[nt];
            }
        bf16x8 Af[2][2];
#pragma unroll
        for (int mt = 0; mt < 2; ++mt)
#pragma unroll
            for (int kk = 0; kk < 2; ++kk) {
                int row  = w * 32 + mt * 16 + lrow;
                int addr = (row * 128 + kk * 64 + lq * 16) ^ ((row & 7) << 4);
                Af[mt][kk] = *(const bf16x8*)(Ab + addr);
            }
#pragma unroll
        for (int mt = 0; mt < 2; ++mt)
#pragma unroll
            for (int nt = 0; nt < 8; ++nt) {
                acc[mt][nt] = __builtin_amdgcn_mfma_f32_16x16x32_bf16(Af[mt][0], Bf[nt][0], acc[mt][nt], 0, 0, 0);
                acc[mt][nt] = __builtin_amdgcn_mfma_f32_16x16x32_bf16(Af[mt][1], Bf[nt][1], acc[mt][nt], 0, 0, 0);
            }
#pragma unroll
        for (int mt = 0; mt < 2; ++mt) {
#pragma unroll
            for (int j = 0; j < 4; ++j) {
                const int row = w * 32 + mt * 16 + lq * 4 + j;
                const int e   = e0 + row;
                const int s   = src[e];
                const int d   = dst[e];
                if (lrow == 0) atomicAdd(cnt + d, 1.0f);
                const u16* hp = H1 + (size_t)s * 128;
                float* op = out + (size_t)d * 128;
#pragma unroll
                for (int nt = 0; nt < 8; ++nt) {
                    const int col = nt * 16 + lrow;
                    float v = fmaxf(acc[mt][nt][j] + bf2f(hp[col]), 0.0f);
                    atomicAdd(op + col, v);
                }
            }
        }
        __syncthreads();
    }
}

__global__ void finalize_kernel(float* __restrict__ out, const float* __restrict__ cnt,
                                const u16* __restrict__ HS) {
    const int stride = gridDim.x * blockDim.x;
    for (int i = blockIdx.x * blockDim.x + threadIdx.x; i < N_NODES * 32; i += stride) {
        const int row = i >> 5;
        const float inv = 1.0f / fmaxf(cnt[row], 1.0f);
        float4 v = ((const float4*)out)[i];
        ushort4 hs = ((const ushort4*)HS)[i];
        float4 r;
        r.x = v.x * inv + bf2f(hs.x);
        r.y = v.y * inv + bf2f(hs.y);
        r.z = v.z * inv + bf2f(hs.z);
        r.w = v.w * inv + bf2f(hs.w);
        ((float4*)out)[i] = r;
    }
}

// ---------------------------------------------------------------------------
extern "C" void kernel_launch(void* const* d_in, const int* in_sizes, int n_in,
                              void* d_out, int out_size, void* d_ws, size_t ws_size,
                              hipStream_t stream) {
    const float* nfeat  = (const float*)d_in[0];
    const float* efeat  = (const float*)d_in[1];
    const int*   src    = (const int*)d_in[2];
    const int*   dst    = (const int*)d_in[3];
    const float* W_edge = (const float*)d_in[4];
    const float* W_ne   = (const float*)d_in[5];
    const float* b_ne   = (const float*)d_in[6];
    const float* W_self = (const float*)d_in[7];
    const float* b_self = (const float*)d_in[8];

    float* out = (float*)d_out;
    char* ws = (char*)d_ws;

    // CSR-path ws layout
    const size_t OFF_W2   = 0;                         // 32768 B
    const size_t OFF_H1   = 32768;                     // 12.8 MB
    const size_t OFF_HS   = OFF_H1 + 12800000;
    const size_t OFF_CNT  = OFF_HS + 12800000;         // 200000 B
    const size_t OFF_OFFS = OFF_CNT + 200000;          // 200064 B
    const size_t OFF_RANK = OFF_OFFS + 200064;         // 3.2 MB
    const size_t OFF_EID  = OFF_RANK + 3200000;        // 3.2 MB
    const size_t OFF_M    = OFF_EID + 3200000;         // 204.8 MB
    const size_t NEED_CSR = OFF_M + 204800000;         // ~237.2 MB

    if (ws_size >= NEED_CSR) {
        float* W2fT = (float*)(ws + OFF_W2);
        u16*   H1   = (u16*)(ws + OFF_H1);
        u16*   HS   = (u16*)(ws + OFF_HS);
        int*   cnts = (int*)(ws + OFF_CNT);
        int*   offs = (int*)(ws + OFF_OFFS);
        int*   rank = (int*)(ws + OFF_RANK);
        int*   eid  = (int*)(ws + OFF_EID);
        u16*   mbuf = (u16*)(ws + OFF_M);

        hipMemsetAsync(cnts, 0, N_NODES * sizeof(int), stream);
        fuse_w2_kernel<<<32, 256, 0, stream>>>(W_edge, W_ne, W2fT);
        node_gemm_kernel<<<1536, 128, 0, stream>>>(nfeat, W_ne, nullptr, H1, N_NODES);
        node_gemm_kernel<<<1536, 128, 0, stream>>>(nfeat, W_self, b_self, HS, N_NODES);
        count_rank_kernel<<<(N_EDGES + 255) / 256, 256, 0, stream>>>(dst, cnts, rank);
        scan_kernel<<<1, SCAN_T, 0, stream>>>(cnts, offs);
        scatter_kernel<<<(N_EDGES + 255) / 256, 256, 0, stream>>>(dst, rank, offs, eid);
        edge_gemm_m_kernel<<<2048, 256, 0, stream>>>(efeat, src, W2fT, b_ne, H1, mbuf);
        csr_reduce_kernel<<<(N_NODES + 1) / 2, 256, 0, stream>>>(eid, offs, mbuf, HS, out);
    } else {
        // round-2 fallback (ws >= ~25.8 MB proven available)
        float* W2fT = (float*)ws;
        float* cntf = (float*)(ws + 32768);
        u16*   H1   = (u16*)(ws + 233472);
        u16*   HS   = (u16*)(ws + 233472 + 12800000);

        zero_kernel<<<1024, 256, 0, stream>>>(out, cntf);
        fuse_w2_kernel<<<32, 256, 0, stream>>>(W_edge, W_ne, W2fT);
        node_gemm_kernel<<<1536, 128, 0, stream>>>(nfeat, W_ne, nullptr, H1, N_NODES);
        node_gemm_kernel<<<1536, 128, 0, stream>>>(nfeat, W_self, b_self, HS, N_NODES);
        edge_mfma_kernel<<<2048, 256, 0, stream>>>(efeat, src, dst, W2fT, b_ne, H1, out, cntf);
        finalize_kernel<<<1024, 256, 0, stream>>>(out, cntf, HS);
    }
}